// Round 4
// baseline (449.915 us; speedup 1.0000x reference)
//
#include <hip/hip_runtime.h>
#include <stdint.h>

typedef unsigned short u16;
typedef __attribute__((ext_vector_type(8))) short bf16x8;
typedef __attribute__((ext_vector_type(4))) float f32x4;

__device__ __forceinline__ u16 f2b(float f) {
  uint32_t u = __float_as_uint(f);
  u += 0x7fffu + ((u >> 16) & 1u);
  return (u16)(u >> 16);
}
__device__ __forceinline__ float b2f(u16 h) {
  return __uint_as_float(((uint32_t)h) << 16);
}

__device__ __forceinline__ void gload_lds16(const u16* g, u16* l) {
  __builtin_amdgcn_global_load_lds(
      (const __attribute__((address_space(1))) void*)g,
      (__attribute__((address_space(3))) void*)l, 16, 0, 0);
}

// ---------------- GEMM: C[m,n] = sum_k A[m,k] * Bt[n,k] ------------------
// A: [M,K] bf16 row-major (lda), Bt: [N,K] bf16 row-major (ldb).
// 128x128 tile, BK=32, 4 waves each computing 64x64 via 4x4 MFMA 16x16x32.
// Block mapping: linear id -> batch = lin&7 (XCD colocation, verified r3:
// FETCH 254->38 MB), then x (fastest), y, part. gridDim.z must be 8*nparts.
// Split-K: K is the PER-PART length; C += part*pStride.
// LDS XOR swizzle kills ds_read_b128 bank conflicts (verified r2).
// bf16/f32 epilogues stage each 32x128 sub-tile through LDS so global
// stores are dwordx4 instead of scalar (r3: scalar stores made the EXP
// epilogue as expensive as the whole K-loop).
enum { EPI_BF16 = 0, EPI_F32 = 1, EPI_RELU_BF16 = 2, EPI_BF16_T = 3,
       EPI_EXP = 4, EPI_BF16_SQ = 5 };

template <int EPI>
__global__ __launch_bounds__(256, 2) void gemm_nt(
    const u16* __restrict__ A, size_t sA, int lda,
    const u16* __restrict__ B, size_t sB, int ldb,
    void* __restrict__ C, size_t sC, int ldc, int K, size_t pStride,
    const float* __restrict__ e_q2, const float* __restrict__ e_k2,
    float* __restrict__ e_l) {
  __shared__ __align__(16) u16 smem[2 * 128 * 32];
  u16* As = smem;
  u16* Bs = smem + 128 * 32;
  const int t = threadIdx.x;
  const int lin = blockIdx.x + gridDim.x * (blockIdx.y + gridDim.y * blockIdx.z);
  const int batch = lin & 7;
  int rest = lin >> 3;
  const int bx = rest % gridDim.x;
  const int ry = rest / gridDim.x;
  const int by = ry % gridDim.y;
  const int part = ry / gridDim.y;
  const int m0 = by * 128, n0 = bx * 128;
  const int koff = part * K;
  const u16* Ab = A + (size_t)batch * sA + (size_t)m0 * lda + koff;
  const u16* Bb = B + (size_t)batch * sB + (size_t)n0 * ldb + koff;
  const int ar0 = t >> 2;
  const int ar1 = ar0 + 64;
  const int ac0 = (((t & 3) ^ ((t >> 3) & 3)) << 3);
  const int w = t >> 6, lane = t & 63;
  const int wm = (w >> 1) << 6, wn = (w & 1) << 6;
  const int qd = lane >> 4, l16 = lane & 15;
  const int pc8 = ((qd ^ ((l16 >> 1) & 3)) << 3);  // phys chunk * 8 for reads

  f32x4 acc[4][4];
#pragma unroll
  for (int i = 0; i < 4; i++)
#pragma unroll
    for (int j = 0; j < 4; j++) acc[i][j] = (f32x4)0.0f;

  for (int k0 = 0; k0 < K; k0 += 32) {
    gload_lds16(Ab + (size_t)ar0 * lda + (k0 + ac0), As + t * 8);
    gload_lds16(Ab + (size_t)ar1 * lda + (k0 + ac0), As + (t + 256) * 8);
    gload_lds16(Bb + (size_t)ar0 * ldb + (k0 + ac0), Bs + t * 8);
    gload_lds16(Bb + (size_t)ar1 * ldb + (k0 + ac0), Bs + (t + 256) * 8);
    __syncthreads();  // drains vmcnt before barrier
    bf16x8 af[4], bfr[4];
#pragma unroll
    for (int i = 0; i < 4; i++)
      af[i] = *(const bf16x8*)(As + (wm + i * 16 + l16) * 32 + pc8);
#pragma unroll
    for (int i = 0; i < 4; i++)
      bfr[i] = *(const bf16x8*)(Bs + (wn + i * 16 + l16) * 32 + pc8);
#pragma unroll
    for (int mi = 0; mi < 4; mi++)
#pragma unroll
      for (int ni = 0; ni < 4; ni++)
        acc[mi][ni] = __builtin_amdgcn_mfma_f32_16x16x32_bf16(
            af[mi], bfr[ni], acc[mi][ni], 0, 0, 0);
    __syncthreads();
  }

  // C/D layout: col = lane&15, row = (lane>>4)*4 + r  (m89-verified)
  const size_t cbase = (size_t)part * pStride + (size_t)batch * sC;
  const int mrows = (int)(sC / ldc);  // rows per batch (for e_l / e_q2 bases)
  const int rl0 = (w >> 1) << 4;      // local row base within 32-row sub-tile

  if constexpr (EPI == EPI_BF16_T) {
    // transposed store: C[col][row], 4 consecutive rows per lane -> ushort4
#pragma unroll
    for (int mi = 0; mi < 4; mi++) {
      const int row0 = m0 + wm + mi * 16 + qd * 4;
#pragma unroll
      for (int ni = 0; ni < 4; ni++) {
        const int col = n0 + wn + ni * 16 + l16;
        ushort4 o = make_ushort4(f2b(acc[mi][ni][0]), f2b(acc[mi][ni][1]),
                                 f2b(acc[mi][ni][2]), f2b(acc[mi][ni][3]));
        *(ushort4*)((u16*)C + cbase + (size_t)col * ldc + row0) = o;
      }
    }
  } else if constexpr (EPI == EPI_F32) {
    float* fs = (float*)smem;  // 32x128 fp32 = 16 KB
#pragma unroll
    for (int mi = 0; mi < 4; mi++) {
      if (mi) __syncthreads();
#pragma unroll
      for (int ni = 0; ni < 4; ni++)
#pragma unroll
        for (int r = 0; r < 4; r++)
          fs[(rl0 + qd * 4 + r) * 128 + wn + ni * 16 + l16] = acc[mi][ni][r];
      __syncthreads();
      const int rl = t >> 3, ck = t & 7;
      const int grow = m0 + ((rl & 16) << 2) + mi * 16 + (rl & 15);
      float* dst = (float*)C + cbase + (size_t)grow * ldc + n0 + ck * 16;
      const float4* src = (const float4*)(fs + rl * 128 + ck * 16);
#pragma unroll
      for (int j = 0; j < 4; j++) ((float4*)dst)[j] = src[j];
    }
  } else if constexpr (EPI == EPI_EXP) {
    // P = exp(sqrt(max(q2+k2-2*acc,0))) bf16; row sums -> atomicAdd(e_l)
    const float* q2b = e_q2 + (size_t)batch * mrows;
    const float* k2b = e_k2 + (size_t)batch * ldc;
    float* lb = e_l + (size_t)batch * mrows;
    float k2v[4];
#pragma unroll
    for (int ni = 0; ni < 4; ni++) k2v[ni] = k2b[n0 + wn + ni * 16 + l16];
#pragma unroll
    for (int mi = 0; mi < 4; mi++) {
      if (mi) __syncthreads();
      float rs[4] = {0.f, 0.f, 0.f, 0.f};
#pragma unroll
      for (int r = 0; r < 4; r++) {
        const int row = m0 + wm + mi * 16 + qd * 4 + r;
        const float q2v = q2b[row];
#pragma unroll
        for (int ni = 0; ni < 4; ni++) {
          const float d2 = fmaxf(q2v + k2v[ni] - 2.0f * acc[mi][ni][r], 0.0f);
          const u16 pb = f2b(__expf(sqrtf(d2)));
          smem[(rl0 + qd * 4 + r) * 128 + wn + ni * 16 + l16] = pb;
          rs[r] += b2f(pb);
        }
      }
#pragma unroll
      for (int r = 0; r < 4; r++) {
#pragma unroll
        for (int off = 1; off < 16; off <<= 1) rs[r] += __shfl_xor(rs[r], off);
      }
      if (l16 == 0) {
        const int row0 = m0 + wm + mi * 16 + qd * 4;
#pragma unroll
        for (int r = 0; r < 4; r++) atomicAdd(lb + row0 + r, rs[r]);
      }
      __syncthreads();
      const int rl = t >> 3, ck = t & 7;
      const int grow = m0 + ((rl & 16) << 2) + mi * 16 + (rl & 15);
      u16* dst = (u16*)C + cbase + (size_t)grow * ldc + n0 + ck * 16;
      const bf16x8* src = (const bf16x8*)(smem + rl * 128 + ck * 16);
      ((bf16x8*)dst)[0] = src[0];
      ((bf16x8*)dst)[1] = src[1];
    }
  } else {
    // EPI_BF16 / EPI_RELU_BF16 / EPI_BF16_SQ via LDS-staged vector stores
#pragma unroll
    for (int mi = 0; mi < 4; mi++) {
      if (mi) __syncthreads();
      float rs[4] = {0.f, 0.f, 0.f, 0.f};
#pragma unroll
      for (int r = 0; r < 4; r++) {
#pragma unroll
        for (int ni = 0; ni < 4; ni++) {
          float v = acc[mi][ni][r];
          if (EPI == EPI_RELU_BF16) v = fmaxf(v, 0.0f);
          const u16 vb = f2b(v);
          smem[(rl0 + qd * 4 + r) * 128 + wn + ni * 16 + l16] = vb;
          if (EPI == EPI_BF16_SQ) { const float vf = b2f(vb); rs[r] += vf * vf; }
        }
      }
      if (EPI == EPI_BF16_SQ) {
#pragma unroll
        for (int r = 0; r < 4; r++) {
#pragma unroll
          for (int off = 1; off < 16; off <<= 1) rs[r] += __shfl_xor(rs[r], off);
        }
        if (l16 == 0) {
          const int row0 = m0 + wm + mi * 16 + qd * 4;
#pragma unroll
          for (int r = 0; r < 4; r++)
            atomicAdd(e_l + (size_t)batch * mrows + row0 + r, rs[r]);
        }
      }
      __syncthreads();
      const int rl = t >> 3, ck = t & 7;
      const int grow = m0 + ((rl & 16) << 2) + mi * 16 + (rl & 15);
      u16* dst = (u16*)C + cbase + (size_t)grow * ldc + n0 + ck * 16;
      const bf16x8* src = (const bf16x8*)(smem + rl * 128 + ck * 16);
      ((bf16x8*)dst)[0] = src[0];
      ((bf16x8*)dst)[1] = src[1];
    }
  }
}

// msg[i] = bf16((p0+p1)/l[row]) over 2 split-K fp32 partials, float4 each
__global__ __launch_bounds__(256) void reduce2_div_bf16(
    const float* __restrict__ P, const float* __restrict__ l,
    u16* __restrict__ out) {
  const size_t i = (size_t)blockIdx.x * 256 + threadIdx.x;  // float4 index
  const float4* p = (const float4*)P;
  float4 a = p[i];
  float4 b = p[i + 1048576];
  const float inv = 1.0f / l[i >> 7];
  ushort4 o = make_ushort4(f2b((a.x + b.x) * inv), f2b((a.y + b.y) * inv),
                           f2b((a.z + b.z) * inv), f2b((a.w + b.w) * inv));
  *(ushort4*)(out + (i << 2)) = o;
}

// ---------------- aux kernels ------------------
__global__ __launch_bounds__(256) void cast_x_to_h(const float* __restrict__ x,
                                                   u16* __restrict__ h, int total4) {
  int i = blockIdx.x * blockDim.x + threadIdx.x;
  if (i >= total4) return;
  const float4 f = ((const float4*)x)[i];
  int e = i << 2;
  int row = e >> 9, col = e & 511;
  ushort4 o = make_ushort4(f2b(f.x), f2b(f.y), f2b(f.z), f2b(f.w));
  *(ushort4*)(h + ((size_t)row << 10) + col) = o;
}

__global__ __launch_bounds__(256) void cast_bf16(const float* __restrict__ in,
                                                 u16* __restrict__ out, int total4) {
  int i = blockIdx.x * blockDim.x + threadIdx.x;
  if (i >= total4) return;
  const float4 f = ((const float4*)in)[i];
  ushort4 o = make_ushort4(f2b(f.x), f2b(f.y), f2b(f.z), f2b(f.w));
  *(ushort4*)(out + ((size_t)i << 2)) = o;
}

// WT[c][r] = bf16(W[r][c]);  W: [R,Cn] fp32
__global__ void transpose_cast_w(const float* __restrict__ W, u16* __restrict__ WT,
                                 int R, int Cn) {
  __shared__ float tile[32][33];
  int c0 = blockIdx.x * 32, r0 = blockIdx.y * 32;
  int tx = threadIdx.x, ty = threadIdx.y;
  for (int i = ty; i < 32; i += 8) tile[i][tx] = W[(size_t)(r0 + i) * Cn + c0 + tx];
  __syncthreads();
  for (int i = ty; i < 32; i += 8) WT[(size_t)(c0 + i) * R + r0 + tx] = f2b(tile[tx][i]);
}

// h[row][512..1023] = bf16(LN(mm[row]; g,b)); 128 thr/row, float4 each
__global__ __launch_bounds__(128) void ln_to_h(const float* __restrict__ mm,
                                               const float* __restrict__ g,
                                               const float* __restrict__ b,
                                               u16* __restrict__ h) {
  const size_t row = blockIdx.x;
  const int t = threadIdx.x;
  const float4 f = ((const float4*)(mm + row * 512))[t];
  float s = f.x + f.y + f.z + f.w;
  float sq = f.x * f.x + f.y * f.y + f.z * f.z + f.w * f.w;
#pragma unroll
  for (int off = 32; off; off >>= 1) { s += __shfl_xor(s, off); sq += __shfl_xor(sq, off); }
  __shared__ float rs_[2], rq_[2];
  if ((t & 63) == 0) { rs_[t >> 6] = s; rq_[t >> 6] = sq; }
  __syncthreads();
  s = rs_[0] + rs_[1]; sq = rq_[0] + rq_[1];
  const float mu = s * (1.0f / 512.0f);
  const float rstd = rsqrtf(sq * (1.0f / 512.0f) - mu * mu + 1e-5f);
  const float4 gv = ((const float4*)g)[t], bv = ((const float4*)b)[t];
  ushort4 o = make_ushort4(f2b((f.x - mu) * rstd * gv.x + bv.x),
                           f2b((f.y - mu) * rstd * gv.y + bv.y),
                           f2b((f.z - mu) * rstd * gv.z + bv.z),
                           f2b((f.w - mu) * rstd * gv.w + bv.w));
  *(ushort4*)(h + (row << 10) + 512 + (t << 2)) = o;
}

// out[row] = x[row] + LN(m2[row]; g,b)
__global__ __launch_bounds__(128) void ln_residual(const float* __restrict__ m2,
                                                   const float* __restrict__ x,
                                                   const float* __restrict__ g,
                                                   const float* __restrict__ b,
                                                   float* __restrict__ out) {
  const size_t row = blockIdx.x;
  const int t = threadIdx.x;
  const float4 f = ((const float4*)(m2 + row * 512))[t];
  float s = f.x + f.y + f.z + f.w;
  float sq = f.x * f.x + f.y * f.y + f.z * f.z + f.w * f.w;
#pragma unroll
  for (int off = 32; off; off >>= 1) { s += __shfl_xor(s, off); sq += __shfl_xor(sq, off); }
  __shared__ float rs_[2], rq_[2];
  if ((t & 63) == 0) { rs_[t >> 6] = s; rq_[t >> 6] = sq; }
  __syncthreads();
  s = rs_[0] + rs_[1]; sq = rq_[0] + rq_[1];
  const float mu = s * (1.0f / 512.0f);
  const float rstd = rsqrtf(sq * (1.0f / 512.0f) - mu * mu + 1e-5f);
  const float4 gv = ((const float4*)g)[t], bv = ((const float4*)b)[t];
  const float4 xv = ((const float4*)(x + row * 512))[t];
  float4 o;
  o.x = xv.x + (f.x - mu) * rstd * gv.x + bv.x;
  o.y = xv.y + (f.y - mu) * rstd * gv.y + bv.y;
  o.z = xv.z + (f.z - mu) * rstd * gv.z + bv.z;
  o.w = xv.w + (f.w - mu) * rstd * gv.w + bv.w;
  ((float4*)(out + row * 512))[t] = o;
}

extern "C" void kernel_launch(void* const* d_in, const int* in_sizes, int n_in,
                              void* d_out, int out_size, void* d_ws, size_t ws_size,
                              hipStream_t stream) {
  const float* x  = (const float*)d_in[0];
  const float* sc = (const float*)d_in[1];
  const float* Wq = (const float*)d_in[2];
  const float* Wk = (const float*)d_in[3];
  const float* Wv = (const float*)d_in[4];
  const float* Wm = (const float*)d_in[5];
  const float* W1 = (const float*)d_in[6];
  const float* W2 = (const float*)d_in[7];
  const float* g1 = (const float*)d_in[8];
  const float* b1 = (const float*)d_in[9];
  const float* g2 = (const float*)d_in[10];
  const float* b2 = (const float*)d_in[11];
  float* out = (float*)d_out;
  char* ws = (char*)d_ws;

  constexpr int N = 8, L = 1024, S = 4096, D = 512;
  // workspace layout (bytes); peak = 231,899,136 (~221 MB)
  u16*   h   = (u16*)(ws + 0);          // [N*L,1024] bf16: x | ln1(message)
  u16*   sb  = (u16*)(ws + 16777216);   // [N*S,512] bf16 source
  u16*   WqT = (u16*)(ws + 50331648);
  u16*   WkT = (u16*)(ws + 50855936);
  u16*   WvT = (u16*)(ws + 51380224);
  u16*   WmT = (u16*)(ws + 51904512);
  u16*   W1T = (u16*)(ws + 52428800);   // [1024,1024]
  u16*   W2T = (u16*)(ws + 54525952);   // [512,1024]
  u16*   q   = (u16*)(ws + 55574528);   // [N*L,512]
  u16*   kb  = (u16*)(ws + 63963136);   // [N*S,512] (dead after qk gemm)
  u16*   vT  = (u16*)(ws + 97517568);   // [N][512,S] bf16 (v written transposed)
  float* lsum= (float*)(ws + 131072000);// [N*L] fp32 row sums of P
  float* q2  = (float*)(ws + 164626432);
  float* k2  = (float*)(ws + 164659200);
  u16*   qk  = (u16*)(ws + 164790272);  // [N*L,S] bf16 P = exp(dist), unnormalized
  u16*   msg = (u16*)(ws + 55574528);   // over q (dead after qk)
  float* mpart = (float*)(ws + 63963136); // [2][N*L,512] f32 over kb (dead), 32 MB
  float* mm  = (float*)(ws + 63963136); // over mpart (dead after reduce)
  u16*   hh  = (u16*)(ws + 80740352);   // 16 MB
  float* m2  = (float*)(ws + 97517568); // over vT (dead after attn.v)

  // phase 0: casts + weight transposes
  cast_x_to_h<<<dim3(4096), 256, 0, stream>>>(x, h, N * L * D / 4);
  cast_bf16<<<dim3(16384), 256, 0, stream>>>(sc, sb, N * S * D / 4);
  transpose_cast_w<<<dim3(16, 16), dim3(32, 8), 0, stream>>>(Wq, WqT, 512, 512);
  transpose_cast_w<<<dim3(16, 16), dim3(32, 8), 0, stream>>>(Wk, WkT, 512, 512);
  transpose_cast_w<<<dim3(16, 16), dim3(32, 8), 0, stream>>>(Wv, WvT, 512, 512);
  transpose_cast_w<<<dim3(16, 16), dim3(32, 8), 0, stream>>>(Wm, WmT, 512, 512);
  transpose_cast_w<<<dim3(32, 32), dim3(32, 8), 0, stream>>>(W1, W1T, 1024, 1024);
  transpose_cast_w<<<dim3(16, 32), dim3(32, 8), 0, stream>>>(W2, W2T, 1024, 512);
  hipMemsetAsync(q2, 0, (size_t)(N * L + N * S + 32) * sizeof(float), stream);
  hipMemsetAsync(lsum, 0, (size_t)N * L * sizeof(float), stream);

  // phase 1: projections (sumsq fused; v written pre-transposed)
  gemm_nt<EPI_BF16_SQ><<<dim3(4, 8, 8), 256, 0, stream>>>(
      h, (size_t)L * 1024, 1024, WqT, 0, 512, q, (size_t)L * 512, 512, 512, 0,
      nullptr, nullptr, q2);
  gemm_nt<EPI_BF16_SQ><<<dim3(4, 32, 8), 256, 0, stream>>>(
      sb, (size_t)S * 512, 512, WkT, 0, 512, kb, (size_t)S * 512, 512, 512, 0,
      nullptr, nullptr, k2);
  gemm_nt<EPI_BF16_T><<<dim3(4, 32, 8), 256, 0, stream>>>(
      sb, (size_t)S * 512, 512, WvT, 0, 512, vT, (size_t)D * S, S, 512, 0,
      nullptr, nullptr, nullptr);

  // phase 2: attention. qk gemm fuses exp(dist) + row-sum accumulation;
  // attn.v (split-K=2) consumes unnormalized P; reduce divides by lsum.
  gemm_nt<EPI_EXP><<<dim3(32, 8, 8), 256, 0, stream>>>(
      q, (size_t)L * 512, 512, kb, (size_t)S * 512, 512, qk, (size_t)L * S, S,
      512, 0, q2, k2, lsum);
  gemm_nt<EPI_F32><<<dim3(4, 8, 16), 256, 0, stream>>>(
      qk, (size_t)L * S, S, vT, (size_t)D * S, S, mpart, (size_t)L * 512, 512,
      2048, (size_t)(N * L) * 512, nullptr, nullptr, nullptr);
  reduce2_div_bf16<<<dim3(4096), 256, 0, stream>>>(mpart, lsum, msg);

  // phase 3: message proj + LN1 into h
  gemm_nt<EPI_F32><<<dim3(4, 8, 8), 256, 0, stream>>>(
      msg, (size_t)L * 512, 512, WmT, 0, 512, mm, (size_t)L * 512, 512, 512, 0,
      nullptr, nullptr, nullptr);
  ln_to_h<<<dim3(N * L), 128, 0, stream>>>(mm, g1, b1, h);

  // phase 4: FFN
  gemm_nt<EPI_RELU_BF16><<<dim3(8, 8, 8), 256, 0, stream>>>(
      h, (size_t)L * 1024, 1024, W1T, 0, 1024, hh, (size_t)L * 1024, 1024, 1024,
      0, nullptr, nullptr, nullptr);
  gemm_nt<EPI_F32><<<dim3(4, 8, 8), 256, 0, stream>>>(
      hh, (size_t)L * 1024, 1024, W2T, 0, 1024, m2, (size_t)L * 512, 512, 1024,
      0, nullptr, nullptr, nullptr);

  // phase 5: LN2 + residual
  ln_residual<<<dim3(N * L), 128, 0, stream>>>(m2, x, g2, b2, out);
}

// Round 5
// 440.106 us; speedup vs baseline: 1.0223x; 1.0223x over previous
//
#include <hip/hip_runtime.h>
#include <stdint.h>

typedef unsigned short u16;
typedef __attribute__((ext_vector_type(8))) short bf16x8;
typedef __attribute__((ext_vector_type(4))) float f32x4;

__device__ __forceinline__ u16 f2b(float f) {
  uint32_t u = __float_as_uint(f);
  u += 0x7fffu + ((u >> 16) & 1u);
  return (u16)(u >> 16);
}
__device__ __forceinline__ float b2f(u16 h) {
  return __uint_as_float(((uint32_t)h) << 16);
}

__device__ __forceinline__ void gload_lds16(const u16* g, u16* l) {
  __builtin_amdgcn_global_load_lds(
      (const __attribute__((address_space(1))) void*)g,
      (__attribute__((address_space(3))) void*)l, 16, 0, 0);
}

// ---------------- GEMM: D[m,n] = sum_k A[m,k] * Bt[n,k] ------------------
// A: [M,K] bf16 row-major (lda), Bt: [N,K] bf16 row-major (ldb).
// 128x128 tile, BK=32, 4 waves each computing 64x64 via 4x4 MFMA 16x16x32.
// ALL epilogues store TRANSPOSED: C[col*ldc + row], vectorized over the 4
// consecutive rows each lane holds (MFMA C/D layout) -> ushort4/float4
// register-direct stores, no LDS staging (r4 showed LDS staging 8-way bank
// conflicts; r3 showed scalar stores cost as much as the K-loop).
// Usage pattern: A = weight/vT (the operand whose transpose we want), Bt =
// activations; the transposed store then lands the output row-major.
// Block mapping: linear id -> batch = lin&7 (XCD colocation, r3: FETCH
// 254->38 MB), then x, y, part. gridDim.z = 8*nparts. Split-K: K = per-part
// length, C += part*pStride. LDS XOR swizzle on staging (r2: conflicts -> 0).
enum { EPI_BF16_T = 0, EPI_BF16_T_SQ = 1, EPI_F32_T = 2, EPI_RELU_BF16_T = 3,
       EPI_EXP_T = 4 };

template <int EPI>
__global__ __launch_bounds__(256, 2) void gemm_nt(
    const u16* __restrict__ A, size_t sA, int lda,
    const u16* __restrict__ B, size_t sB, int ldb,
    void* __restrict__ C, size_t sC, int ldc, int K, size_t pStride,
    const float* __restrict__ e_col2, const float* __restrict__ e_row2,
    float* __restrict__ e_l) {
  __shared__ __align__(16) u16 As[128 * 32];
  __shared__ __align__(16) u16 Bs[128 * 32];
  const int t = threadIdx.x;
  const int lin = blockIdx.x + gridDim.x * (blockIdx.y + gridDim.y * blockIdx.z);
  const int batch = lin & 7;
  int rest = lin >> 3;
  const int bx = rest % gridDim.x;
  const int ry = rest / gridDim.x;
  const int by = ry % gridDim.y;
  const int part = ry / gridDim.y;
  const int m0 = by * 128, n0 = bx * 128;
  const int koff = part * K;
  const u16* Ab = A + (size_t)batch * sA + (size_t)m0 * lda + koff;
  const u16* Bb = B + (size_t)batch * sB + (size_t)n0 * ldb + koff;
  const int ar0 = t >> 2;
  const int ar1 = ar0 + 64;
  const int ac0 = (((t & 3) ^ ((t >> 3) & 3)) << 3);
  const int w = t >> 6, lane = t & 63;
  const int wm = (w >> 1) << 6, wn = (w & 1) << 6;
  const int qd = lane >> 4, l16 = lane & 15;
  const int pc8 = ((qd ^ ((l16 >> 1) & 3)) << 3);  // phys chunk * 8 for reads

  f32x4 acc[4][4];
#pragma unroll
  for (int i = 0; i < 4; i++)
#pragma unroll
    for (int j = 0; j < 4; j++) acc[i][j] = (f32x4)0.0f;

  for (int k0 = 0; k0 < K; k0 += 32) {
    gload_lds16(Ab + (size_t)ar0 * lda + (k0 + ac0), As + t * 8);
    gload_lds16(Ab + (size_t)ar1 * lda + (k0 + ac0), As + (t + 256) * 8);
    gload_lds16(Bb + (size_t)ar0 * ldb + (k0 + ac0), Bs + t * 8);
    gload_lds16(Bb + (size_t)ar1 * ldb + (k0 + ac0), Bs + (t + 256) * 8);
    __syncthreads();  // drains vmcnt before barrier
    bf16x8 af[4], bfr[4];
#pragma unroll
    for (int i = 0; i < 4; i++)
      af[i] = *(const bf16x8*)(As + (wm + i * 16 + l16) * 32 + pc8);
#pragma unroll
    for (int i = 0; i < 4; i++)
      bfr[i] = *(const bf16x8*)(Bs + (wn + i * 16 + l16) * 32 + pc8);
#pragma unroll
    for (int mi = 0; mi < 4; mi++)
#pragma unroll
      for (int ni = 0; ni < 4; ni++)
        acc[mi][ni] = __builtin_amdgcn_mfma_f32_16x16x32_bf16(
            af[mi], bfr[ni], acc[mi][ni], 0, 0, 0);
    __syncthreads();
  }

  // C/D layout: col = lane&15, row = (lane>>4)*4 + r  (m89-verified).
  // Transposed store: C[col*ldc + row0 .. row0+3] per (mi,ni).
  const size_t cbase = (size_t)part * pStride + (size_t)batch * sC;
  const int ncols = (int)(sC / ldc);  // per-batch col count for e_l/e_col2

  if constexpr (EPI == EPI_EXP_T) {
    // result[s,l]; P = exp(sqrt(max(q2[l]+k2[s]-2*acc,0))) bf16, T-stored as
    // P[l,s]; col(l)-sums over s -> atomicAdd(e_l[l]).
    const int nrows = (int)(sA / lda);
    const float* col2 = e_col2 + (size_t)batch * ncols;  // q2 by l
    const float* row2 = e_row2 + (size_t)batch * nrows;  // k2 by s
    float* lb = e_l + (size_t)batch * ncols;
    float cs[4] = {0.f, 0.f, 0.f, 0.f};
    float c2v[4];
#pragma unroll
    for (int ni = 0; ni < 4; ni++) c2v[ni] = col2[n0 + wn + ni * 16 + l16];
#pragma unroll
    for (int mi = 0; mi < 4; mi++) {
      const int row0 = m0 + wm + mi * 16 + qd * 4;
      float r2v[4];
#pragma unroll
      for (int r = 0; r < 4; r++) r2v[r] = row2[row0 + r];
#pragma unroll
      for (int ni = 0; ni < 4; ni++) {
        const int col = n0 + wn + ni * 16 + l16;
        u16 pb[4];
#pragma unroll
        for (int r = 0; r < 4; r++) {
          const float d2 = fmaxf(c2v[ni] + r2v[r] - 2.0f * acc[mi][ni][r], 0.0f);
          pb[r] = f2b(__expf(sqrtf(d2)));
          cs[ni] += b2f(pb[r]);
        }
        *(ushort4*)((u16*)C + cbase + (size_t)col * ldc + row0) =
            make_ushort4(pb[0], pb[1], pb[2], pb[3]);
      }
    }
#pragma unroll
    for (int ni = 0; ni < 4; ni++) {
      cs[ni] += __shfl_xor(cs[ni], 16);
      cs[ni] += __shfl_xor(cs[ni], 32);
    }
    if (qd == 0) {
#pragma unroll
      for (int ni = 0; ni < 4; ni++)
        atomicAdd(lb + n0 + wn + ni * 16 + l16, cs[ni]);
    }
  } else if constexpr (EPI == EPI_F32_T) {
#pragma unroll
    for (int mi = 0; mi < 4; mi++) {
      const int row0 = m0 + wm + mi * 16 + qd * 4;
#pragma unroll
      for (int ni = 0; ni < 4; ni++) {
        const int col = n0 + wn + ni * 16 + l16;
        *(f32x4*)((float*)C + cbase + (size_t)col * ldc + row0) = acc[mi][ni];
      }
    }
  } else {
    // EPI_BF16_T / EPI_BF16_T_SQ / EPI_RELU_BF16_T
    float cs[4] = {0.f, 0.f, 0.f, 0.f};
#pragma unroll
    for (int mi = 0; mi < 4; mi++) {
      const int row0 = m0 + wm + mi * 16 + qd * 4;
#pragma unroll
      for (int ni = 0; ni < 4; ni++) {
        const int col = n0 + wn + ni * 16 + l16;
        u16 vb[4];
#pragma unroll
        for (int r = 0; r < 4; r++) {
          float v = acc[mi][ni][r];
          if (EPI == EPI_RELU_BF16_T) v = fmaxf(v, 0.0f);
          vb[r] = f2b(v);
          if (EPI == EPI_BF16_T_SQ) {
            const float vf = b2f(vb[r]);
            cs[ni] += vf * vf;
          }
        }
        *(ushort4*)((u16*)C + cbase + (size_t)col * ldc + row0) =
            make_ushort4(vb[0], vb[1], vb[2], vb[3]);
      }
    }
    if (EPI == EPI_BF16_T_SQ) {
#pragma unroll
      for (int ni = 0; ni < 4; ni++) {
        cs[ni] += __shfl_xor(cs[ni], 16);
        cs[ni] += __shfl_xor(cs[ni], 32);
      }
      if (qd == 0) {
#pragma unroll
        for (int ni = 0; ni < 4; ni++)
          atomicAdd(e_l + (size_t)batch * ncols + n0 + wn + ni * 16 + l16,
                    cs[ni]);
      }
    }
  }
}

// msg[i] = bf16((p0+p1)/l[row]) over 2 split-K fp32 partials, float4 each
__global__ __launch_bounds__(256) void reduce2_div_bf16(
    const float* __restrict__ P, const float* __restrict__ l,
    u16* __restrict__ out) {
  const size_t i = (size_t)blockIdx.x * 256 + threadIdx.x;  // float4 index
  const float4* p = (const float4*)P;
  float4 a = p[i];
  float4 b = p[i + 1048576];
  const float inv = 1.0f / l[i >> 7];
  ushort4 o = make_ushort4(f2b((a.x + b.x) * inv), f2b((a.y + b.y) * inv),
                           f2b((a.z + b.z) * inv), f2b((a.w + b.w) * inv));
  *(ushort4*)(out + (i << 2)) = o;
}

// ---------------- aux kernels ------------------
__global__ __launch_bounds__(256) void cast_x_to_h(const float* __restrict__ x,
                                                   u16* __restrict__ h, int total4) {
  int i = blockIdx.x * blockDim.x + threadIdx.x;
  if (i >= total4) return;
  const float4 f = ((const float4*)x)[i];
  int e = i << 2;
  int row = e >> 9, col = e & 511;
  ushort4 o = make_ushort4(f2b(f.x), f2b(f.y), f2b(f.z), f2b(f.w));
  *(ushort4*)(h + ((size_t)row << 10) + col) = o;
}

__global__ __launch_bounds__(256) void cast_bf16(const float* __restrict__ in,
                                                 u16* __restrict__ out, int total4) {
  int i = blockIdx.x * blockDim.x + threadIdx.x;
  if (i >= total4) return;
  const float4 f = ((const float4*)in)[i];
  ushort4 o = make_ushort4(f2b(f.x), f2b(f.y), f2b(f.z), f2b(f.w));
  *(ushort4*)(out + ((size_t)i << 2)) = o;
}

// WT[c][r] = bf16(W[r][c]);  W: [R,Cn] fp32
__global__ void transpose_cast_w(const float* __restrict__ W, u16* __restrict__ WT,
                                 int R, int Cn) {
  __shared__ float tile[32][33];
  int c0 = blockIdx.x * 32, r0 = blockIdx.y * 32;
  int tx = threadIdx.x, ty = threadIdx.y;
  for (int i = ty; i < 32; i += 8) tile[i][tx] = W[(size_t)(r0 + i) * Cn + c0 + tx];
  __syncthreads();
  for (int i = ty; i < 32; i += 8) WT[(size_t)(c0 + i) * R + r0 + tx] = f2b(tile[tx][i]);
}

// h[row][512..1023] = bf16(LN(mm[row]; g,b)); 128 thr/row, float4 each
__global__ __launch_bounds__(128) void ln_to_h(const float* __restrict__ mm,
                                               const float* __restrict__ g,
                                               const float* __restrict__ b,
                                               u16* __restrict__ h) {
  const size_t row = blockIdx.x;
  const int t = threadIdx.x;
  const float4 f = ((const float4*)(mm + row * 512))[t];
  float s = f.x + f.y + f.z + f.w;
  float sq = f.x * f.x + f.y * f.y + f.z * f.z + f.w * f.w;
#pragma unroll
  for (int off = 32; off; off >>= 1) { s += __shfl_xor(s, off); sq += __shfl_xor(sq, off); }
  __shared__ float rs_[2], rq_[2];
  if ((t & 63) == 0) { rs_[t >> 6] = s; rq_[t >> 6] = sq; }
  __syncthreads();
  s = rs_[0] + rs_[1]; sq = rq_[0] + rq_[1];
  const float mu = s * (1.0f / 512.0f);
  const float rstd = rsqrtf(sq * (1.0f / 512.0f) - mu * mu + 1e-5f);
  const float4 gv = ((const float4*)g)[t], bv = ((const float4*)b)[t];
  ushort4 o = make_ushort4(f2b((f.x - mu) * rstd * gv.x + bv.x),
                           f2b((f.y - mu) * rstd * gv.y + bv.y),
                           f2b((f.z - mu) * rstd * gv.z + bv.z),
                           f2b((f.w - mu) * rstd * gv.w + bv.w));
  *(ushort4*)(h + (row << 10) + 512 + (t << 2)) = o;
}

// out[row] = x[row] + LN(m2[row]; g,b)
__global__ __launch_bounds__(128) void ln_residual(const float* __restrict__ m2,
                                                   const float* __restrict__ x,
                                                   const float* __restrict__ g,
                                                   const float* __restrict__ b,
                                                   float* __restrict__ out) {
  const size_t row = blockIdx.x;
  const int t = threadIdx.x;
  const float4 f = ((const float4*)(m2 + row * 512))[t];
  float s = f.x + f.y + f.z + f.w;
  float sq = f.x * f.x + f.y * f.y + f.z * f.z + f.w * f.w;
#pragma unroll
  for (int off = 32; off; off >>= 1) { s += __shfl_xor(s, off); sq += __shfl_xor(sq, off); }
  __shared__ float rs_[2], rq_[2];
  if ((t & 63) == 0) { rs_[t >> 6] = s; rq_[t >> 6] = sq; }
  __syncthreads();
  s = rs_[0] + rs_[1]; sq = rq_[0] + rq_[1];
  const float mu = s * (1.0f / 512.0f);
  const float rstd = rsqrtf(sq * (1.0f / 512.0f) - mu * mu + 1e-5f);
  const float4 gv = ((const float4*)g)[t], bv = ((const float4*)b)[t];
  const float4 xv = ((const float4*)(x + row * 512))[t];
  float4 o;
  o.x = xv.x + (f.x - mu) * rstd * gv.x + bv.x;
  o.y = xv.y + (f.y - mu) * rstd * gv.y + bv.y;
  o.z = xv.z + (f.z - mu) * rstd * gv.z + bv.z;
  o.w = xv.w + (f.w - mu) * rstd * gv.w + bv.w;
  ((float4*)(out + row * 512))[t] = o;
}

extern "C" void kernel_launch(void* const* d_in, const int* in_sizes, int n_in,
                              void* d_out, int out_size, void* d_ws, size_t ws_size,
                              hipStream_t stream) {
  const float* x  = (const float*)d_in[0];
  const float* sc = (const float*)d_in[1];
  const float* Wq = (const float*)d_in[2];
  const float* Wk = (const float*)d_in[3];
  const float* Wv = (const float*)d_in[4];
  const float* Wm = (const float*)d_in[5];
  const float* W1 = (const float*)d_in[6];
  const float* W2 = (const float*)d_in[7];
  const float* g1 = (const float*)d_in[8];
  const float* b1 = (const float*)d_in[9];
  const float* g2 = (const float*)d_in[10];
  const float* b2 = (const float*)d_in[11];
  float* out = (float*)d_out;
  char* ws = (char*)d_ws;

  constexpr int N = 8, L = 1024, S = 4096, D = 512;
  // workspace layout (bytes); peak = 231,899,136 (~221 MB)
  u16*   h   = (u16*)(ws + 0);          // [N*L,1024] bf16: x | ln1(message)
  u16*   sb  = (u16*)(ws + 16777216);   // [N*S,512] bf16 source
  u16*   WqT = (u16*)(ws + 50331648);
  u16*   WkT = (u16*)(ws + 50855936);
  u16*   WvT = (u16*)(ws + 51380224);
  u16*   WmT = (u16*)(ws + 51904512);
  u16*   W1T = (u16*)(ws + 52428800);   // [1024,1024]
  u16*   W2T = (u16*)(ws + 54525952);   // [512,1024]
  u16*   q   = (u16*)(ws + 55574528);   // [N*L,512]
  u16*   kb  = (u16*)(ws + 63963136);   // [N*S,512] (dead after qk gemm)
  u16*   vT  = (u16*)(ws + 97517568);   // [N][512,S] bf16 (v written transposed)
  float* lsum= (float*)(ws + 131072000);// [N*L] fp32 col sums of P
  float* q2  = (float*)(ws + 164626432);
  float* k2  = (float*)(ws + 164659200);
  u16*   qk  = (u16*)(ws + 164790272);  // [N*L,S] bf16 P = exp(dist), unnormalized
  u16*   msg = (u16*)(ws + 55574528);   // over q (dead after qk)
  float* mpart = (float*)(ws + 63963136); // [2][N*L,512] f32 over kb (dead), 32 MB
  float* mm  = (float*)(ws + 63963136); // over mpart (dead after reduce)
  u16*   hh  = (u16*)(ws + 80740352);   // 16 MB
  float* m2  = (float*)(ws + 97517568); // over vT (dead after attn.v)

  // phase 0: casts + weight transposes
  cast_x_to_h<<<dim3(4096), 256, 0, stream>>>(x, h, N * L * D / 4);
  cast_bf16<<<dim3(16384), 256, 0, stream>>>(sc, sb, N * S * D / 4);
  transpose_cast_w<<<dim3(16, 16), dim3(32, 8), 0, stream>>>(Wq, WqT, 512, 512);
  transpose_cast_w<<<dim3(16, 16), dim3(32, 8), 0, stream>>>(Wk, WkT, 512, 512);
  transpose_cast_w<<<dim3(16, 16), dim3(32, 8), 0, stream>>>(Wv, WvT, 512, 512);
  transpose_cast_w<<<dim3(16, 16), dim3(32, 8), 0, stream>>>(Wm, WmT, 512, 512);
  transpose_cast_w<<<dim3(32, 32), dim3(32, 8), 0, stream>>>(W1, W1T, 1024, 1024);
  transpose_cast_w<<<dim3(16, 32), dim3(32, 8), 0, stream>>>(W2, W2T, 1024, 512);
  hipMemsetAsync(q2, 0, (size_t)(N * L + N * S + 32) * sizeof(float), stream);
  hipMemsetAsync(lsum, 0, (size_t)N * L * sizeof(float), stream);

  // phase 1: projections, swapped (A=weight) + transposed store -> row-major
  // q-proj: result[d,l] -> q[l,d]; sumsq over d fused -> q2[l]
  gemm_nt<EPI_BF16_T_SQ><<<dim3(8, 4, 8), 256, 0, stream>>>(
      WqT, 0, 512, h, (size_t)L * 1024, 1024, q, (size_t)L * 512, 512, 512, 0,
      nullptr, nullptr, q2);
  gemm_nt<EPI_BF16_T_SQ><<<dim3(32, 4, 8), 256, 0, stream>>>(
      WkT, 0, 512, sb, (size_t)S * 512, 512, kb, (size_t)S * 512, 512, 512, 0,
      nullptr, nullptr, k2);
  // v-proj: A=sb, result[s,c] -> T-store vT[c,s]
  gemm_nt<EPI_BF16_T><<<dim3(4, 32, 8), 256, 0, stream>>>(
      sb, (size_t)S * 512, 512, WvT, 0, 512, vT, (size_t)D * S, S, 512, 0,
      nullptr, nullptr, nullptr);

  // phase 2: attention. EXP gemm swapped: A=kb (rows s), Bt=q (cols l);
  // T-store lands P[l,s]; col sums -> lsum[l]. attn.v swapped: A=vT, Bt=P,
  // split-K=2, T-store f32 -> mpart[l,c]; reduce divides by lsum.
  gemm_nt<EPI_EXP_T><<<dim3(8, 32, 8), 256, 0, stream>>>(
      kb, (size_t)S * 512, 512, q, (size_t)L * 512, 512, qk, (size_t)L * S, S,
      512, 0, q2, k2, lsum);
  gemm_nt<EPI_F32_T><<<dim3(8, 4, 16), 256, 0, stream>>>(
      vT, (size_t)D * S, S, qk, (size_t)L * S, S, mpart, (size_t)L * 512, 512,
      2048, (size_t)(N * L) * 512, nullptr, nullptr, nullptr);
  reduce2_div_bf16<<<dim3(4096), 256, 0, stream>>>(mpart, lsum, msg);

  // phase 3: message proj (swapped) + LN1 into h
  gemm_nt<EPI_F32_T><<<dim3(8, 4, 8), 256, 0, stream>>>(
      WmT, 0, 512, msg, (size_t)L * 512, 512, mm, (size_t)L * 512, 512, 512, 0,
      nullptr, nullptr, nullptr);
  ln_to_h<<<dim3(N * L), 128, 0, stream>>>(mm, g1, b1, h);

  // phase 4: FFN, both swapped
  gemm_nt<EPI_RELU_BF16_T><<<dim3(8, 8, 8), 256, 0, stream>>>(
      W1T, 0, 1024, h, (size_t)L * 1024, 1024, hh, (size_t)L * 1024, 1024, 1024,
      0, nullptr, nullptr, nullptr);
  gemm_nt<EPI_F32_T><<<dim3(8, 4, 8), 256, 0, stream>>>(
      W2T, 0, 1024, hh, (size_t)L * 1024, 1024, m2, (size_t)L * 512, 512, 1024,
      0, nullptr, nullptr, nullptr);

  // phase 5: LN2 + residual
  ln_residual<<<dim3(N * L), 128, 0, stream>>>(m2, x, g2, b2, out);
}

// Round 6
// 402.443 us; speedup vs baseline: 1.1180x; 1.0936x over previous
//
#include <hip/hip_runtime.h>
#include <stdint.h>

typedef unsigned short u16;
typedef __attribute__((ext_vector_type(8))) short bf16x8;
typedef __attribute__((ext_vector_type(4))) float f32x4;
typedef __attribute__((ext_vector_type(4))) unsigned int u32x4;

__device__ __forceinline__ u16 f2b(float f) {
  uint32_t u = __float_as_uint(f);
  u += 0x7fffu + ((u >> 16) & 1u);
  return (u16)(u >> 16);
}
__device__ __forceinline__ float b2f(u16 h) {
  return __uint_as_float(((uint32_t)h) << 16);
}
// pack two f32 -> two bf16 (RTNE); HW packed cvt when available
__device__ __forceinline__ uint32_t pack2bf(float a, float b) {
#if __has_builtin(__builtin_amdgcn_cvt_pk_bf16_f32)
  typedef __attribute__((ext_vector_type(2))) __bf16 bf16x2_t;
  bf16x2_t r = __builtin_amdgcn_cvt_pk_bf16_f32(a, b);
  return __builtin_bit_cast(uint32_t, r);
#else
  return (uint32_t)f2b(a) | ((uint32_t)f2b(b) << 16);
#endif
}

__device__ __forceinline__ void gload_lds16(const u16* g, u16* l) {
  __builtin_amdgcn_global_load_lds(
      (const __attribute__((address_space(1))) void*)g,
      (__attribute__((address_space(3))) void*)l, 16, 0, 0);
}

// ---------------- GEMM: D[m,n] = sum_k A[m,k] * Bt[n,k] ------------------
// A: [M,K] bf16 row-major (lda), Bt: [N,K] bf16 row-major (ldb).
// 128x128 tile, BK=32, 4 waves, 4x4 MFMA 16x16x32 each.
// A-ROW REMAP (r6): MFMA block mi's logical row j is loaded from physical
// tile row (j>>2)*8 + (j&3) + {0,4,32,36}[mi]. Then lane (qd) holds
// physical rows qd*8..+7 in acc[0..1] and 32+qd*8..+7 in acc[2..3] for each
// col -> transposed stores are 16-B (bf16) / 2x16-B (f32) contiguous chunks,
// half the store count of r5's 8-B stores, no extra K-loop cost.
// Transposed-store usage: A = the operand whose transpose we want in the
// output (weights / vT / kb), Bt = activations.
// Block mapping: linear id -> batch = lin&7 (XCD colocation, r3: FETCH
// 254->38 MB), then x, y, part. Split-K: K = per-part len, C += part*pStride.
// LDS XOR swizzle on staging kills bank conflicts (r2); A-frag swizzle key
// gains an (i&1) bit from the +4 row offset of odd mi blocks.
enum { EPI_BF16_T = 0, EPI_BF16_T_SQ = 1, EPI_F32_T = 2, EPI_RELU_BF16_T = 3,
       EPI_EXP_T = 4 };

template <int EPI>
__device__ __forceinline__ void gemm_body(
    u16* smem, const u16* A, size_t sA, int lda,
    const u16* B, size_t sB, int ldb,
    void* C, size_t sC, int ldc, int K, size_t pStride,
    const float* e_col2, const float* e_row2, float* e_l,
    int lin, int gx, int gy) {
  u16* As = smem;
  u16* Bs = smem + 4096;
  const int t = threadIdx.x;
  const int batch = lin & 7;
  const int rest = lin >> 3;
  const int bx = rest % gx;
  const int ry = rest / gx;
  const int by = ry % gy;
  const int part = ry / gy;
  const int m0 = by * 128, n0 = bx * 128;
  const int koff = part * K;
  const u16* Ab = A + (size_t)batch * sA + (size_t)m0 * lda + koff;
  const u16* Bb = B + (size_t)batch * sB + (size_t)n0 * ldb + koff;
  const int ar0 = t >> 2;
  const int ar1 = ar0 + 64;
  const int ac0 = (((t & 3) ^ ((t >> 3) & 3)) << 3);
  const int w = t >> 6, lane = t & 63;
  const int wm = (w >> 1) << 6, wn = (w & 1) << 6;
  const int qd = lane >> 4, l16 = lane & 15;
  // A-frag remap: rows rbase+{0,4,32,36}, swizzle key per mi parity
  const int rbase = ((l16 >> 2) << 3) + (l16 & 3);
  const int keylo = (l16 >> 1) & 1;
  const int pcA0 = ((qd ^ keylo) << 3);
  const int pcA1 = ((qd ^ (keylo | 2)) << 3);
  const int pcB = ((qd ^ ((l16 >> 1) & 3)) << 3);

  f32x4 acc[4][4];
#pragma unroll
  for (int i = 0; i < 4; i++)
#pragma unroll
    for (int j = 0; j < 4; j++) acc[i][j] = (f32x4)0.0f;

  for (int k0 = 0; k0 < K; k0 += 32) {
    gload_lds16(Ab + (size_t)ar0 * lda + (k0 + ac0), As + t * 8);
    gload_lds16(Ab + (size_t)ar1 * lda + (k0 + ac0), As + (t + 256) * 8);
    gload_lds16(Bb + (size_t)ar0 * ldb + (k0 + ac0), Bs + t * 8);
    gload_lds16(Bb + (size_t)ar1 * ldb + (k0 + ac0), Bs + (t + 256) * 8);
    __syncthreads();  // drains vmcnt before barrier
    bf16x8 af[4], bfr[4];
    af[0] = *(const bf16x8*)(As + (wm + rbase) * 32 + pcA0);
    af[1] = *(const bf16x8*)(As + (wm + rbase + 4) * 32 + pcA1);
    af[2] = *(const bf16x8*)(As + (wm + rbase + 32) * 32 + pcA0);
    af[3] = *(const bf16x8*)(As + (wm + rbase + 36) * 32 + pcA1);
#pragma unroll
    for (int i = 0; i < 4; i++)
      bfr[i] = *(const bf16x8*)(Bs + (wn + i * 16 + l16) * 32 + pcB);
#pragma unroll
    for (int mi = 0; mi < 4; mi++)
#pragma unroll
      for (int ni = 0; ni < 4; ni++)
        acc[mi][ni] = __builtin_amdgcn_mfma_f32_16x16x32_bf16(
            af[mi], bfr[ni], acc[mi][ni], 0, 0, 0);
    __syncthreads();
  }

  // With remap: acc[2p+h][ni][r] holds phys row m0+wm+p*32+qd*8+h*4+r, col
  // n0+wn+ni*16+l16. Stores: C[col*ldc + row], 8 rows contiguous per (p,ni).
  const size_t cbase = (size_t)part * pStride + (size_t)batch * sC;
  const int ncols = (int)(sC / ldc);

  if constexpr (EPI == EPI_EXP_T) {
    const int nrows = (int)(sA / lda);
    const float* col2 = e_col2 + (size_t)batch * ncols;  // q2 by col (l)
    const float* row2 = e_row2 + (size_t)batch * nrows;  // k2 by row (s)
    float* lb = e_l + (size_t)batch * ncols;
    float c2v[4];
#pragma unroll
    for (int ni = 0; ni < 4; ni++) c2v[ni] = col2[n0 + wn + ni * 16 + l16];
    float cs[4] = {0.f, 0.f, 0.f, 0.f};
#pragma unroll
    for (int p = 0; p < 2; p++) {
      const int prow = m0 + wm + p * 32 + qd * 8;
      float r2v[8];
#pragma unroll
      for (int r8 = 0; r8 < 8; r8++) r2v[r8] = row2[prow + r8];
#pragma unroll
      for (int ni = 0; ni < 4; ni++) {
        const int col = n0 + wn + ni * 16 + l16;
        float pv[8];
#pragma unroll
        for (int r = 0; r < 4; r++) {
          pv[r] = __expf(sqrtf(
              fmaxf(c2v[ni] + r2v[r] - 2.0f * acc[2 * p][ni][r], 0.0f)));
          pv[4 + r] = __expf(sqrtf(
              fmaxf(c2v[ni] + r2v[4 + r] - 2.0f * acc[2 * p + 1][ni][r], 0.0f)));
        }
#pragma unroll
        for (int j = 0; j < 8; j++) cs[ni] += pv[j];
        u32x4 wv;
        wv[0] = pack2bf(pv[0], pv[1]);
        wv[1] = pack2bf(pv[2], pv[3]);
        wv[2] = pack2bf(pv[4], pv[5]);
        wv[3] = pack2bf(pv[6], pv[7]);
        *(u32x4*)((u16*)C + cbase + (size_t)col * ldc + prow) = wv;
      }
    }
#pragma unroll
    for (int ni = 0; ni < 4; ni++) {
      cs[ni] += __shfl_xor(cs[ni], 16);
      cs[ni] += __shfl_xor(cs[ni], 32);
    }
    if (qd == 0) {
#pragma unroll
      for (int ni = 0; ni < 4; ni++)
        atomicAdd(lb + n0 + wn + ni * 16 + l16, cs[ni]);
    }
  } else if constexpr (EPI == EPI_F32_T) {
#pragma unroll
    for (int p = 0; p < 2; p++) {
      const int prow = m0 + wm + p * 32 + qd * 8;
#pragma unroll
      for (int ni = 0; ni < 4; ni++) {
        const int col = n0 + wn + ni * 16 + l16;
        float* dst = (float*)C + cbase + (size_t)col * ldc + prow;
        *(f32x4*)dst = acc[2 * p][ni];
        *(f32x4*)(dst + 4) = acc[2 * p + 1][ni];
      }
    }
  } else {
    // EPI_BF16_T / EPI_BF16_T_SQ / EPI_RELU_BF16_T
    float cs[4] = {0.f, 0.f, 0.f, 0.f};
#pragma unroll
    for (int p = 0; p < 2; p++) {
      const int prow = m0 + wm + p * 32 + qd * 8;
#pragma unroll
      for (int ni = 0; ni < 4; ni++) {
        const int col = n0 + wn + ni * 16 + l16;
        float v[8];
#pragma unroll
        for (int r = 0; r < 4; r++) {
          v[r] = acc[2 * p][ni][r];
          v[4 + r] = acc[2 * p + 1][ni][r];
        }
        if (EPI == EPI_RELU_BF16_T) {
#pragma unroll
          for (int j = 0; j < 8; j++) v[j] = fmaxf(v[j], 0.0f);
        }
        if (EPI == EPI_BF16_T_SQ) {
#pragma unroll
          for (int j = 0; j < 8; j++) cs[ni] += v[j] * v[j];
        }
        u32x4 wv;
        wv[0] = pack2bf(v[0], v[1]);
        wv[1] = pack2bf(v[2], v[3]);
        wv[2] = pack2bf(v[4], v[5]);
        wv[3] = pack2bf(v[6], v[7]);
        *(u32x4*)((u16*)C + cbase + (size_t)col * ldc + prow) = wv;
      }
    }
    if (EPI == EPI_BF16_T_SQ) {
#pragma unroll
      for (int ni = 0; ni < 4; ni++) {
        cs[ni] += __shfl_xor(cs[ni], 16);
        cs[ni] += __shfl_xor(cs[ni], 32);
      }
      if (qd == 0) {
#pragma unroll
        for (int ni = 0; ni < 4; ni++)
          atomicAdd(e_l + (size_t)batch * ncols + n0 + wn + ni * 16 + l16,
                    cs[ni]);
      }
    }
  }
}

template <int EPI>
__global__ __launch_bounds__(256, 2) void gemm_nt(
    const u16* __restrict__ A, size_t sA, int lda,
    const u16* __restrict__ B, size_t sB, int ldb,
    void* __restrict__ C, size_t sC, int ldc, int K, size_t pStride,
    const float* __restrict__ e_col2, const float* __restrict__ e_row2,
    float* __restrict__ e_l) {
  __shared__ __align__(16) u16 smem[8192];
  const int lin = blockIdx.x + gridDim.x * (blockIdx.y + gridDim.y * blockIdx.z);
  gemm_body<EPI>(smem, A, sA, lda, B, sB, ldb, C, sC, ldc, K, pStride,
                 e_col2, e_row2, e_l, lin, gridDim.x, gridDim.y);
}

// q/k/v projections in ONE launch (fewer launch gaps; tails overlap).
__global__ __launch_bounds__(256, 2) void proj_fused(
    const u16* __restrict__ WqT, const u16* __restrict__ WkT,
    const u16* __restrict__ WvT, const u16* __restrict__ h,
    const u16* __restrict__ sb, u16* __restrict__ q, u16* __restrict__ kb,
    u16* __restrict__ vT, float* __restrict__ q2, float* __restrict__ k2) {
  __shared__ __align__(16) u16 smem[8192];
  const int lin = blockIdx.x;
  if (lin < 256) {
    // q-proj: result[d,l] -> T-store q[l,d]; col-sumsq -> q2[l]
    gemm_body<EPI_BF16_T_SQ>(smem, WqT, 0, 512, h, (size_t)1024 * 1024, 1024,
                             q, (size_t)1024 * 512, 512, 512, 0, nullptr,
                             nullptr, q2, lin, 8, 4);
  } else if (lin < 1280) {
    // k-proj: result[d,s] -> T-store kb[s,d]; col-sumsq -> k2[s]
    gemm_body<EPI_BF16_T_SQ>(smem, WkT, 0, 512, sb, (size_t)4096 * 512, 512,
                             kb, (size_t)4096 * 512, 512, 512, 0, nullptr,
                             nullptr, k2, lin - 256, 32, 4);
  } else {
    // v-proj: result[s,c] -> T-store vT[c,s]
    gemm_body<EPI_BF16_T>(smem, sb, (size_t)4096 * 512, 512, WvT, 0, 512,
                          vT, (size_t)512 * 4096, 4096, 512, 0, nullptr,
                          nullptr, nullptr, lin - 1280, 4, 32);
  }
}

// msg[i] = bf16((p0+p1)/l[row]) over 2 split-K fp32 partials, float4 each
__global__ __launch_bounds__(256) void reduce2_div_bf16(
    const float* __restrict__ P, const float* __restrict__ l,
    u16* __restrict__ out) {
  const size_t i = (size_t)blockIdx.x * 256 + threadIdx.x;  // float4 index
  const float4* p = (const float4*)P;
  float4 a = p[i];
  float4 b = p[i + 1048576];
  const float inv = 1.0f / l[i >> 7];
  ushort4 o = make_ushort4(f2b((a.x + b.x) * inv), f2b((a.y + b.y) * inv),
                           f2b((a.z + b.z) * inv), f2b((a.w + b.w) * inv));
  *(ushort4*)(out + (i << 2)) = o;
}

// ---------------- fused prep: cast x->h, source->sb, zero q2/k2/lsum -----
__global__ __launch_bounds__(256) void fused_prep(
    const float* __restrict__ x, const float* __restrict__ sc,
    u16* __restrict__ h, u16* __restrict__ sb, float* __restrict__ q2,
    float* __restrict__ k2, float* __restrict__ lsum) {
  const size_t i = (size_t)blockIdx.x * 256 + threadIdx.x;
  if (i < 1048576) {  // x: [N*L,512] -> h[:, 0:512] (row stride 1024)
    const float4 f = ((const float4*)x)[i];
    const int e = (int)(i << 2);
    const int row = e >> 9, col = e & 511;
    *(ushort4*)(h + ((size_t)row << 10) + col) =
        make_ushort4(f2b(f.x), f2b(f.y), f2b(f.z), f2b(f.w));
  } else if (i < 5242880) {
    const size_t j = i - 1048576;
    const float4 f = ((const float4*)sc)[j];
    *(ushort4*)(sb + (j << 2)) =
        make_ushort4(f2b(f.x), f2b(f.y), f2b(f.z), f2b(f.w));
  } else {
    const size_t j = i - 5242880;
    const float4 z = {0.f, 0.f, 0.f, 0.f};
    if (j < 2048) ((float4*)q2)[j] = z;
    else if (j < 10240) ((float4*)k2)[j - 2048] = z;
    else ((float4*)lsum)[j - 10240] = z;
  }
}

// all 6 weight transposes in one launch; WT[c][r] = bf16(W[r][c])
__global__ void transpose_w6(
    const float* __restrict__ Wq, const float* __restrict__ Wk,
    const float* __restrict__ Wv, const float* __restrict__ Wm,
    const float* __restrict__ W1, const float* __restrict__ W2,
    u16* __restrict__ WqT, u16* __restrict__ WkT, u16* __restrict__ WvT,
    u16* __restrict__ WmT, u16* __restrict__ W1T, u16* __restrict__ W2T) {
  __shared__ float tile[32][33];
  const float* W;
  u16* WT;
  int R, Cn;
  switch (blockIdx.z) {
    case 0: W = Wq; WT = WqT; R = 512; Cn = 512; break;
    case 1: W = Wk; WT = WkT; R = 512; Cn = 512; break;
    case 2: W = Wv; WT = WvT; R = 512; Cn = 512; break;
    case 3: W = Wm; WT = WmT; R = 512; Cn = 512; break;
    case 4: W = W1; WT = W1T; R = 1024; Cn = 1024; break;
    default: W = W2; WT = W2T; R = 1024; Cn = 512; break;
  }
  const int c0 = blockIdx.x * 32, r0 = blockIdx.y * 32;
  if (c0 >= Cn || r0 >= R) return;
  const int tx = threadIdx.x, ty = threadIdx.y;
  for (int i = ty; i < 32; i += 8) tile[i][tx] = W[(size_t)(r0 + i) * Cn + c0 + tx];
  __syncthreads();
  for (int i = ty; i < 32; i += 8) WT[(size_t)(c0 + i) * R + r0 + tx] = f2b(tile[tx][i]);
}

// h[row][512..1023] = bf16(LN(mm[row]; g,b)); 128 thr/row, float4 each
__global__ __launch_bounds__(128) void ln_to_h(const float* __restrict__ mm,
                                               const float* __restrict__ g,
                                               const float* __restrict__ b,
                                               u16* __restrict__ h) {
  const size_t row = blockIdx.x;
  const int t = threadIdx.x;
  const float4 f = ((const float4*)(mm + row * 512))[t];
  float s = f.x + f.y + f.z + f.w;
  float sq = f.x * f.x + f.y * f.y + f.z * f.z + f.w * f.w;
#pragma unroll
  for (int off = 32; off; off >>= 1) { s += __shfl_xor(s, off); sq += __shfl_xor(sq, off); }
  __shared__ float rs_[2], rq_[2];
  if ((t & 63) == 0) { rs_[t >> 6] = s; rq_[t >> 6] = sq; }
  __syncthreads();
  s = rs_[0] + rs_[1]; sq = rq_[0] + rq_[1];
  const float mu = s * (1.0f / 512.0f);
  const float rstd = rsqrtf(sq * (1.0f / 512.0f) - mu * mu + 1e-5f);
  const float4 gv = ((const float4*)g)[t], bv = ((const float4*)b)[t];
  ushort4 o = make_ushort4(f2b((f.x - mu) * rstd * gv.x + bv.x),
                           f2b((f.y - mu) * rstd * gv.y + bv.y),
                           f2b((f.z - mu) * rstd * gv.z + bv.z),
                           f2b((f.w - mu) * rstd * gv.w + bv.w));
  *(ushort4*)(h + (row << 10) + 512 + (t << 2)) = o;
}

// out[row] = x[row] + LN(m2[row]; g,b)
__global__ __launch_bounds__(128) void ln_residual(const float* __restrict__ m2,
                                                   const float* __restrict__ x,
                                                   const float* __restrict__ g,
                                                   const float* __restrict__ b,
                                                   float* __restrict__ out) {
  const size_t row = blockIdx.x;
  const int t = threadIdx.x;
  const float4 f = ((const float4*)(m2 + row * 512))[t];
  float s = f.x + f.y + f.z + f.w;
  float sq = f.x * f.x + f.y * f.y + f.z * f.z + f.w * f.w;
#pragma unroll
  for (int off = 32; off; off >>= 1) { s += __shfl_xor(s, off); sq += __shfl_xor(sq, off); }
  __shared__ float rs_[2], rq_[2];
  if ((t & 63) == 0) { rs_[t >> 6] = s; rq_[t >> 6] = sq; }
  __syncthreads();
  s = rs_[0] + rs_[1]; sq = rq_[0] + rq_[1];
  const float mu = s * (1.0f / 512.0f);
  const float rstd = rsqrtf(sq * (1.0f / 512.0f) - mu * mu + 1e-5f);
  const float4 gv = ((const float4*)g)[t], bv = ((const float4*)b)[t];
  const float4 xv = ((const float4*)(x + row * 512))[t];
  float4 o;
  o.x = xv.x + (f.x - mu) * rstd * gv.x + bv.x;
  o.y = xv.y + (f.y - mu) * rstd * gv.y + bv.y;
  o.z = xv.z + (f.z - mu) * rstd * gv.z + bv.z;
  o.w = xv.w + (f.w - mu) * rstd * gv.w + bv.w;
  ((float4*)(out + row * 512))[t] = o;
}

extern "C" void kernel_launch(void* const* d_in, const int* in_sizes, int n_in,
                              void* d_out, int out_size, void* d_ws, size_t ws_size,
                              hipStream_t stream) {
  const float* x  = (const float*)d_in[0];
  const float* sc = (const float*)d_in[1];
  const float* Wq = (const float*)d_in[2];
  const float* Wk = (const float*)d_in[3];
  const float* Wv = (const float*)d_in[4];
  const float* Wm = (const float*)d_in[5];
  const float* W1 = (const float*)d_in[6];
  const float* W2 = (const float*)d_in[7];
  const float* g1 = (const float*)d_in[8];
  const float* b1 = (const float*)d_in[9];
  const float* g2 = (const float*)d_in[10];
  const float* b2 = (const float*)d_in[11];
  float* out = (float*)d_out;
  char* ws = (char*)d_ws;

  constexpr int N = 8, L = 1024, S = 4096, D = 512;
  // workspace layout (bytes); peak = 231,899,136 (~221 MB)
  u16*   h   = (u16*)(ws + 0);          // [N*L,1024] bf16: x | ln1(message)
  u16*   sb  = (u16*)(ws + 16777216);   // [N*S,512] bf16 source
  u16*   WqT = (u16*)(ws + 50331648);
  u16*   WkT = (u16*)(ws + 50855936);
  u16*   WvT = (u16*)(ws + 51380224);
  u16*   WmT = (u16*)(ws + 51904512);
  u16*   W1T = (u16*)(ws + 52428800);   // [1024,1024]
  u16*   W2T = (u16*)(ws + 54525952);   // [512,1024]
  u16*   q   = (u16*)(ws + 55574528);   // [N*L,512]
  u16*   kb  = (u16*)(ws + 63963136);   // [N*S,512] (dead after qk gemm)
  u16*   vT  = (u16*)(ws + 97517568);   // [N][512,S] bf16 (v written transposed)
  float* lsum= (float*)(ws + 131072000);// [N*L] fp32 col sums of P
  float* q2  = (float*)(ws + 164626432);
  float* k2  = (float*)(ws + 164659200);
  u16*   qk  = (u16*)(ws + 164790272);  // [N*L,S] bf16 P = exp(dist), unnormalized
  u16*   msg = (u16*)(ws + 55574528);   // over q (dead after qk)
  float* mpart = (float*)(ws + 63963136); // [2][N*L,512] f32 over kb (dead), 32 MB
  float* mm  = (float*)(ws + 63963136); // over mpart (dead after reduce)
  u16*   hh  = (u16*)(ws + 80740352);   // 16 MB
  float* m2  = (float*)(ws + 97517568); // over vT (dead after attn.v)

  // phase 0: fused casts+zeroing, fused weight transposes
  fused_prep<<<dim3(20528), 256, 0, stream>>>(x, sc, h, sb, q2, k2, lsum);
  transpose_w6<<<dim3(32, 32, 6), dim3(32, 8), 0, stream>>>(
      Wq, Wk, Wv, Wm, W1, W2, WqT, WkT, WvT, WmT, W1T, W2T);

  // phase 1: q/k/v projections in one launch
  proj_fused<<<dim3(2304), 256, 0, stream>>>(WqT, WkT, WvT, h, sb, q, kb, vT,
                                             q2, k2);

  // phase 2: attention. EXP gemm: A=kb (rows s), Bt=q (cols l); T-store
  // lands P[l,s]; col sums -> lsum[l]. attn.v: A=vT, Bt=P, split-K=2,
  // T-store f32 -> mpart[l,c]; reduce divides by lsum.
  gemm_nt<EPI_EXP_T><<<dim3(8, 32, 8), 256, 0, stream>>>(
      kb, (size_t)S * 512, 512, q, (size_t)L * 512, 512, qk, (size_t)L * S, S,
      512, 0, q2, k2, lsum);
  gemm_nt<EPI_F32_T><<<dim3(8, 4, 16), 256, 0, stream>>>(
      vT, (size_t)D * S, S, qk, (size_t)L * S, S, mpart, (size_t)L * 512, 512,
      2048, (size_t)(N * L) * 512, nullptr, nullptr, nullptr);
  reduce2_div_bf16<<<dim3(4096), 256, 0, stream>>>(mpart, lsum, msg);

  // phase 3: message proj + LN1 into h
  gemm_nt<EPI_F32_T><<<dim3(8, 4, 8), 256, 0, stream>>>(
      WmT, 0, 512, msg, (size_t)L * 512, 512, mm, (size_t)L * 512, 512, 512, 0,
      nullptr, nullptr, nullptr);
  ln_to_h<<<dim3(N * L), 128, 0, stream>>>(mm, g1, b1, h);

  // phase 4: FFN
  gemm_nt<EPI_RELU_BF16_T><<<dim3(8, 8, 8), 256, 0, stream>>>(
      W1T, 0, 1024, h, (size_t)L * 1024, 1024, hh, (size_t)L * 1024, 1024, 1024,
      0, nullptr, nullptr, nullptr);
  gemm_nt<EPI_F32_T><<<dim3(8, 4, 8), 256, 0, stream>>>(
      W2T, 0, 1024, hh, (size_t)L * 1024, 1024, m2, (size_t)L * 512, 512, 1024,
      0, nullptr, nullptr, nullptr);

  // phase 5: LN2 + residual
  ln_residual<<<dim3(N * L), 128, 0, stream>>>(m2, x, g2, b2, out);
}

// Round 7
// 364.386 us; speedup vs baseline: 1.2347x; 1.1044x over previous
//
#include <hip/hip_runtime.h>
#include <stdint.h>

typedef unsigned short u16;
typedef __attribute__((ext_vector_type(8))) short bf16x8;
typedef __attribute__((ext_vector_type(4))) float f32x4;
typedef __attribute__((ext_vector_type(4))) unsigned int u32x4;

__device__ __forceinline__ u16 f2b(float f) {
  uint32_t u = __float_as_uint(f);
  u += 0x7fffu + ((u >> 16) & 1u);
  return (u16)(u >> 16);
}
__device__ __forceinline__ float b2f(u16 h) {
  return __uint_as_float(((uint32_t)h) << 16);
}
// pack two f32 -> two bf16 (RTNE); HW packed cvt when available
__device__ __forceinline__ uint32_t pack2bf(float a, float b) {
#if __has_builtin(__builtin_amdgcn_cvt_pk_bf16_f32)
  typedef __attribute__((ext_vector_type(2))) __bf16 bf16x2_t;
  bf16x2_t r = __builtin_amdgcn_cvt_pk_bf16_f32(a, b);
  return __builtin_bit_cast(uint32_t, r);
#else
  return (uint32_t)f2b(a) | ((uint32_t)f2b(b) << 16);
#endif
}

__device__ __forceinline__ void gload_lds16(const u16* g, u16* l) {
  __builtin_amdgcn_global_load_lds(
      (const __attribute__((address_space(1))) void*)g,
      (__attribute__((address_space(3))) void*)l, 16, 0, 0);
}

// ---------------- GEMM: D[m,n] = sum_k A[m,k] * Bt[n,k] ------------------
// A: [M,K] bf16 row-major (lda), Bt: [N,K] bf16 row-major (ldb).
// 128x128 tile, BK=64 (r7: halves barrier count vs BK=32 — the vmcnt-drain
// at __syncthreads is the structural ~20% stall), 4 waves, 4x4 MFMA
// 16x16x32, two k-steps per staging iter.
// A-ROW REMAP (r6): MFMA block mi's logical row j loaded from physical tile
// row (j>>2)*8+(j&3)+{0,4,32,36}[mi] -> lane qd holds 8 contiguous output
// rows per col -> 16-B transposed stores.
// LDS SWIZZLE (r7): row stride = 128 B = one full bank wrap, so banks
// depend only on the chunk. phys_chunk = logical ^ key(row) with
// key(row) = (row&3) | (((row>>3)&1)<<2): conflict-free (2-way) for BOTH
// the remapped A reads (rows 8a+b -> key b|(a&1)<<2) and linear B reads
// (rows i*16+l16 -> key (l16&3)|(l16>>3)<<2). r6's key missed bit3 ->
// 2.1M conflicts; this restores r2's zero.
// Block mapping: linear id -> batch = lin&7 (XCD colocation, r3: FETCH
// 254->38 MB), then x, y, part. Split-K: K = per-part len, C += part*pStride.
enum { EPI_BF16_T = 0, EPI_BF16_T_SQ = 1, EPI_F32_T = 2, EPI_RELU_BF16_T = 3,
       EPI_EXP_T = 4 };

template <int EPI>
__device__ __forceinline__ void gemm_body(
    u16* smem, const u16* A, size_t sA, int lda,
    const u16* B, size_t sB, int ldb,
    void* C, size_t sC, int ldc, int K, size_t pStride,
    const float* e_col2, const float* e_row2, float* e_l,
    int lin, int gx, int gy) {
  u16* As = smem;          // [128][64] u16
  u16* Bs = smem + 8192;   // [128][64] u16
  const int t = threadIdx.x;
  const int batch = lin & 7;
  const int rest = lin >> 3;
  const int bx = rest % gx;
  const int ry = rest / gx;
  const int by = ry % gy;
  const int part = ry / gy;
  const int m0 = by * 128, n0 = bx * 128;
  const int koff = part * K;
  const u16* Ab = A + (size_t)batch * sA + (size_t)m0 * lda + koff;
  const u16* Bb = B + (size_t)batch * sB + (size_t)n0 * ldb + koff;
  // staging: thread t stages slots {t+256j}: row = slot>>3 = t>>3 + 32j,
  // phys chunk = t&7. key(row) is j-invariant (32j touches neither bits
  // 0..1 nor bit 3). logical col = ((t&7)^key)*8.
  const int srow = t >> 3;
  const int skey = (srow & 3) | (((srow >> 3) & 1) << 2);
  const int scol = ((t & 7) ^ skey) << 3;
  const u16* aS = Ab + (size_t)srow * lda + scol;
  const u16* bS = Bb + (size_t)srow * ldb + scol;
  const size_t a32 = (size_t)32 * lda, b32 = (size_t)32 * ldb;
  u16* asDst = As + t * 8;
  u16* bsDst = Bs + t * 8;

  const int w = t >> 6, lane = t & 63;
  const int wm = (w >> 1) << 6, wn = (w & 1) << 6;
  const int qd = lane >> 4, l16 = lane & 15;
  // A-frag remap rows (phys): rbase + {0,4,32,36}; key shared (bits 0,1,3
  // of all four rows identical).
  const int rbase = ((l16 >> 2) << 3) + (l16 & 3);
  const int keyA = (l16 & 3) | (((l16 >> 2) & 1) << 2);
  const int keyB = (l16 & 3) | (((l16 >> 3) & 1) << 2);
  const u16* aRow0 = As + (wm + rbase) * 64;
  const u16* bRow0 = Bs + (wn + l16) * 64;

  f32x4 acc[4][4];
#pragma unroll
  for (int i = 0; i < 4; i++)
#pragma unroll
    for (int j = 0; j < 4; j++) acc[i][j] = (f32x4)0.0f;

  for (int k0 = 0; k0 < K; k0 += 64) {
    gload_lds16(aS, asDst);
    gload_lds16(aS + a32, asDst + 2048);
    gload_lds16(aS + 2 * a32, asDst + 4096);
    gload_lds16(aS + 3 * a32, asDst + 6144);
    gload_lds16(bS, bsDst);
    gload_lds16(bS + b32, bsDst + 2048);
    gload_lds16(bS + 2 * b32, bsDst + 4096);
    gload_lds16(bS + 3 * b32, bsDst + 6144);
    aS += 64;
    bS += 64;
    __syncthreads();  // drains vmcnt before barrier
#pragma unroll
    for (int s = 0; s < 2; s++) {
      const int ca = (((qd | (s << 2)) ^ keyA) << 3);
      const int cb = (((qd | (s << 2)) ^ keyB) << 3);
      bf16x8 af[4], bfr[4];
      af[0] = *(const bf16x8*)(aRow0 + ca);
      af[1] = *(const bf16x8*)(aRow0 + 4 * 64 + ca);
      af[2] = *(const bf16x8*)(aRow0 + 32 * 64 + ca);
      af[3] = *(const bf16x8*)(aRow0 + 36 * 64 + ca);
#pragma unroll
      for (int i = 0; i < 4; i++)
        bfr[i] = *(const bf16x8*)(bRow0 + i * 16 * 64 + cb);
#pragma unroll
      for (int mi = 0; mi < 4; mi++)
#pragma unroll
        for (int ni = 0; ni < 4; ni++)
          acc[mi][ni] = __builtin_amdgcn_mfma_f32_16x16x32_bf16(
              af[mi], bfr[ni], acc[mi][ni], 0, 0, 0);
    }
    __syncthreads();
  }

  // acc[2p+h][ni][r] holds phys row m0+wm+p*32+qd*8+h*4+r, col
  // n0+wn+ni*16+l16. Transposed stores: 8 contiguous rows per (p,ni).
  const size_t cbase = (size_t)part * pStride + (size_t)batch * sC;
  const int ncols = (int)(sC / ldc);

  if constexpr (EPI == EPI_EXP_T) {
    const int nrows = (int)(sA / lda);
    const float* col2 = e_col2 + (size_t)batch * ncols;  // q2 by col (l)
    const float* row2 = e_row2 + (size_t)batch * nrows;  // k2 by row (s)
    float* lb = e_l + (size_t)batch * ncols;
    float c2v[4];
#pragma unroll
    for (int ni = 0; ni < 4; ni++) c2v[ni] = col2[n0 + wn + ni * 16 + l16];
    float cs[4] = {0.f, 0.f, 0.f, 0.f};
#pragma unroll
    for (int p = 0; p < 2; p++) {
      const int prow = m0 + wm + p * 32 + qd * 8;
      float r2v[8];
#pragma unroll
      for (int r8 = 0; r8 < 8; r8++) r2v[r8] = row2[prow + r8];
#pragma unroll
      for (int ni = 0; ni < 4; ni++) {
        const int col = n0 + wn + ni * 16 + l16;
        float pv[8];
#pragma unroll
        for (int r = 0; r < 4; r++) {
          pv[r] = __expf(sqrtf(
              fmaxf(c2v[ni] + r2v[r] - 2.0f * acc[2 * p][ni][r], 0.0f)));
          pv[4 + r] = __expf(sqrtf(
              fmaxf(c2v[ni] + r2v[4 + r] - 2.0f * acc[2 * p + 1][ni][r], 0.0f)));
        }
#pragma unroll
        for (int j = 0; j < 8; j++) cs[ni] += pv[j];
        u32x4 wv;
        wv[0] = pack2bf(pv[0], pv[1]);
        wv[1] = pack2bf(pv[2], pv[3]);
        wv[2] = pack2bf(pv[4], pv[5]);
        wv[3] = pack2bf(pv[6], pv[7]);
        *(u32x4*)((u16*)C + cbase + (size_t)col * ldc + prow) = wv;
      }
    }
#pragma unroll
    for (int ni = 0; ni < 4; ni++) {
      cs[ni] += __shfl_xor(cs[ni], 16);
      cs[ni] += __shfl_xor(cs[ni], 32);
    }
    if (qd == 0) {
#pragma unroll
      for (int ni = 0; ni < 4; ni++)
        atomicAdd(lb + n0 + wn + ni * 16 + l16, cs[ni]);
    }
  } else if constexpr (EPI == EPI_F32_T) {
#pragma unroll
    for (int p = 0; p < 2; p++) {
      const int prow = m0 + wm + p * 32 + qd * 8;
#pragma unroll
      for (int ni = 0; ni < 4; ni++) {
        const int col = n0 + wn + ni * 16 + l16;
        float* dst = (float*)C + cbase + (size_t)col * ldc + prow;
        *(f32x4*)dst = acc[2 * p][ni];
        *(f32x4*)(dst + 4) = acc[2 * p + 1][ni];
      }
    }
  } else {
    // EPI_BF16_T / EPI_BF16_T_SQ / EPI_RELU_BF16_T
    float cs[4] = {0.f, 0.f, 0.f, 0.f};
#pragma unroll
    for (int p = 0; p < 2; p++) {
      const int prow = m0 + wm + p * 32 + qd * 8;
#pragma unroll
      for (int ni = 0; ni < 4; ni++) {
        const int col = n0 + wn + ni * 16 + l16;
        float v[8];
#pragma unroll
        for (int r = 0; r < 4; r++) {
          v[r] = acc[2 * p][ni][r];
          v[4 + r] = acc[2 * p + 1][ni][r];
        }
        if (EPI == EPI_RELU_BF16_T) {
#pragma unroll
          for (int j = 0; j < 8; j++) v[j] = fmaxf(v[j], 0.0f);
        }
        if (EPI == EPI_BF16_T_SQ) {
#pragma unroll
          for (int j = 0; j < 8; j++) cs[ni] += v[j] * v[j];
        }
        u32x4 wv;
        wv[0] = pack2bf(v[0], v[1]);
        wv[1] = pack2bf(v[2], v[3]);
        wv[2] = pack2bf(v[4], v[5]);
        wv[3] = pack2bf(v[6], v[7]);
        *(u32x4*)((u16*)C + cbase + (size_t)col * ldc + prow) = wv;
      }
    }
    if (EPI == EPI_BF16_T_SQ) {
#pragma unroll
      for (int ni = 0; ni < 4; ni++) {
        cs[ni] += __shfl_xor(cs[ni], 16);
        cs[ni] += __shfl_xor(cs[ni], 32);
      }
      if (qd == 0) {
#pragma unroll
        for (int ni = 0; ni < 4; ni++)
          atomicAdd(e_l + (size_t)batch * ncols + n0 + wn + ni * 16 + l16,
                    cs[ni]);
      }
    }
  }
}

template <int EPI>
__global__ __launch_bounds__(256, 2) void gemm_nt(
    const u16* __restrict__ A, size_t sA, int lda,
    const u16* __restrict__ B, size_t sB, int ldb,
    void* __restrict__ C, size_t sC, int ldc, int K, size_t pStride,
    const float* __restrict__ e_col2, const float* __restrict__ e_row2,
    float* __restrict__ e_l) {
  __shared__ __align__(16) u16 smem[16384];
  const int lin = blockIdx.x + gridDim.x * (blockIdx.y + gridDim.y * blockIdx.z);
  gemm_body<EPI>(smem, A, sA, lda, B, sB, ldb, C, sC, ldc, K, pStride,
                 e_col2, e_row2, e_l, lin, gridDim.x, gridDim.y);
}

// q/k/v projections in ONE launch (fewer launch gaps; tails overlap).
__global__ __launch_bounds__(256, 2) void proj_fused(
    const u16* __restrict__ WqT, const u16* __restrict__ WkT,
    const u16* __restrict__ WvT, const u16* __restrict__ h,
    const u16* __restrict__ sb, u16* __restrict__ q, u16* __restrict__ kb,
    u16* __restrict__ vT, float* __restrict__ q2, float* __restrict__ k2) {
  __shared__ __align__(16) u16 smem[16384];
  const int lin = blockIdx.x;
  if (lin < 256) {
    // q-proj: result[d,l] -> T-store q[l,d]; col-sumsq -> q2[l]
    gemm_body<EPI_BF16_T_SQ>(smem, WqT, 0, 512, h, (size_t)1024 * 1024, 1024,
                             q, (size_t)1024 * 512, 512, 512, 0, nullptr,
                             nullptr, q2, lin, 8, 4);
  } else if (lin < 1280) {
    // k-proj: result[d,s] -> T-store kb[s,d]; col-sumsq -> k2[s]
    gemm_body<EPI_BF16_T_SQ>(smem, WkT, 0, 512, sb, (size_t)4096 * 512, 512,
                             kb, (size_t)4096 * 512, 512, 512, 0, nullptr,
                             nullptr, k2, lin - 256, 32, 4);
  } else {
    // v-proj: result[s,c] -> T-store vT[c,s]
    gemm_body<EPI_BF16_T>(smem, sb, (size_t)4096 * 512, 512, WvT, 0, 512,
                          vT, (size_t)512 * 4096, 4096, 512, 0, nullptr,
                          nullptr, nullptr, lin - 1280, 4, 32);
  }
}

// msg[i] = bf16((p0+p1)/l[row]) over 2 split-K fp32 partials, float4 each
__global__ __launch_bounds__(256) void reduce2_div_bf16(
    const float* __restrict__ P, const float* __restrict__ l,
    u16* __restrict__ out) {
  const size_t i = (size_t)blockIdx.x * 256 + threadIdx.x;  // float4 index
  const float4* p = (const float4*)P;
  float4 a = p[i];
  float4 b = p[i + 1048576];
  const float inv = 1.0f / l[i >> 7];
  ushort4 o = make_ushort4(f2b((a.x + b.x) * inv), f2b((a.y + b.y) * inv),
                           f2b((a.z + b.z) * inv), f2b((a.w + b.w) * inv));
  *(ushort4*)(out + (i << 2)) = o;
}

// ---------------- fused prep: cast x->h, source->sb, zero q2/k2/lsum -----
__global__ __launch_bounds__(256) void fused_prep(
    const float* __restrict__ x, const float* __restrict__ sc,
    u16* __restrict__ h, u16* __restrict__ sb, float* __restrict__ q2,
    float* __restrict__ k2, float* __restrict__ lsum) {
  const size_t i = (size_t)blockIdx.x * 256 + threadIdx.x;
  if (i < 1048576) {  // x: [N*L,512] -> h[:, 0:512] (row stride 1024)
    const float4 f = ((const float4*)x)[i];
    const int e = (int)(i << 2);
    const int row = e >> 9, col = e & 511;
    *(ushort4*)(h + ((size_t)row << 10) + col) =
        make_ushort4(f2b(f.x), f2b(f.y), f2b(f.z), f2b(f.w));
  } else if (i < 5242880) {
    const size_t j = i - 1048576;
    const float4 f = ((const float4*)sc)[j];
    *(ushort4*)(sb + (j << 2)) =
        make_ushort4(f2b(f.x), f2b(f.y), f2b(f.z), f2b(f.w));
  } else {
    const size_t j = i - 5242880;
    const float4 z = {0.f, 0.f, 0.f, 0.f};
    if (j < 2048) ((float4*)q2)[j] = z;
    else if (j < 10240) ((float4*)k2)[j - 2048] = z;
    else ((float4*)lsum)[j - 10240] = z;
  }
}

// all 6 weight transposes in one launch; WT[c][r] = bf16(W[r][c])
__global__ void transpose_w6(
    const float* __restrict__ Wq, const float* __restrict__ Wk,
    const float* __restrict__ Wv, const float* __restrict__ Wm,
    const float* __restrict__ W1, const float* __restrict__ W2,
    u16* __restrict__ WqT, u16* __restrict__ WkT, u16* __restrict__ WvT,
    u16* __restrict__ WmT, u16* __restrict__ W1T, u16* __restrict__ W2T) {
  __shared__ float tile[32][33];
  const float* W;
  u16* WT;
  int R, Cn;
  switch (blockIdx.z) {
    case 0: W = Wq; WT = WqT; R = 512; Cn = 512; break;
    case 1: W = Wk; WT = WkT; R = 512; Cn = 512; break;
    case 2: W = Wv; WT = WvT; R = 512; Cn = 512; break;
    case 3: W = Wm; WT = WmT; R = 512; Cn = 512; break;
    case 4: W = W1; WT = W1T; R = 1024; Cn = 1024; break;
    default: W = W2; WT = W2T; R = 1024; Cn = 512; break;
  }
  const int c0 = blockIdx.x * 32, r0 = blockIdx.y * 32;
  if (c0 >= Cn || r0 >= R) return;
  const int tx = threadIdx.x, ty = threadIdx.y;
  for (int i = ty; i < 32; i += 8) tile[i][tx] = W[(size_t)(r0 + i) * Cn + c0 + tx];
  __syncthreads();
  for (int i = ty; i < 32; i += 8) WT[(size_t)(c0 + i) * R + r0 + tx] = f2b(tile[tx][i]);
}

// h[row][512..1023] = bf16(LN(mm[row]; g,b)); 128 thr/row, float4 each
__global__ __launch_bounds__(128) void ln_to_h(const float* __restrict__ mm,
                                               const float* __restrict__ g,
                                               const float* __restrict__ b,
                                               u16* __restrict__ h) {
  const size_t row = blockIdx.x;
  const int t = threadIdx.x;
  const float4 f = ((const float4*)(mm + row * 512))[t];
  float s = f.x + f.y + f.z + f.w;
  float sq = f.x * f.x + f.y * f.y + f.z * f.z + f.w * f.w;
#pragma unroll
  for (int off = 32; off; off >>= 1) { s += __shfl_xor(s, off); sq += __shfl_xor(sq, off); }
  __shared__ float rs_[2], rq_[2];
  if ((t & 63) == 0) { rs_[t >> 6] = s; rq_[t >> 6] = sq; }
  __syncthreads();
  s = rs_[0] + rs_[1]; sq = rq_[0] + rq_[1];
  const float mu = s * (1.0f / 512.0f);
  const float rstd = rsqrtf(sq * (1.0f / 512.0f) - mu * mu + 1e-5f);
  const float4 gv = ((const float4*)g)[t], bv = ((const float4*)b)[t];
  ushort4 o = make_ushort4(f2b((f.x - mu) * rstd * gv.x + bv.x),
                           f2b((f.y - mu) * rstd * gv.y + bv.y),
                           f2b((f.z - mu) * rstd * gv.z + bv.z),
                           f2b((f.w - mu) * rstd * gv.w + bv.w));
  *(ushort4*)(h + (row << 10) + 512 + (t << 2)) = o;
}

// out[row] = x[row] + LN(m2[row]; g,b)
__global__ __launch_bounds__(128) void ln_residual(const float* __restrict__ m2,
                                                   const float* __restrict__ x,
                                                   const float* __restrict__ g,
                                                   const float* __restrict__ b,
                                                   float* __restrict__ out) {
  const size_t row = blockIdx.x;
  const int t = threadIdx.x;
  const float4 f = ((const float4*)(m2 + row * 512))[t];
  float s = f.x + f.y + f.z + f.w;
  float sq = f.x * f.x + f.y * f.y + f.z * f.z + f.w * f.w;
#pragma unroll
  for (int off = 32; off; off >>= 1) { s += __shfl_xor(s, off); sq += __shfl_xor(sq, off); }
  __shared__ float rs_[2], rq_[2];
  if ((t & 63) == 0) { rs_[t >> 6] = s; rq_[t >> 6] = sq; }
  __syncthreads();
  s = rs_[0] + rs_[1]; sq = rq_[0] + rq_[1];
  const float mu = s * (1.0f / 512.0f);
  const float rstd = rsqrtf(sq * (1.0f / 512.0f) - mu * mu + 1e-5f);
  const float4 gv = ((const float4*)g)[t], bv = ((const float4*)b)[t];
  const float4 xv = ((const float4*)(x + row * 512))[t];
  float4 o;
  o.x = xv.x + (f.x - mu) * rstd * gv.x + bv.x;
  o.y = xv.y + (f.y - mu) * rstd * gv.y + bv.y;
  o.z = xv.z + (f.z - mu) * rstd * gv.z + bv.z;
  o.w = xv.w + (f.w - mu) * rstd * gv.w + bv.w;
  ((float4*)(out + row * 512))[t] = o;
}

extern "C" void kernel_launch(void* const* d_in, const int* in_sizes, int n_in,
                              void* d_out, int out_size, void* d_ws, size_t ws_size,
                              hipStream_t stream) {
  const float* x  = (const float*)d_in[0];
  const float* sc = (const float*)d_in[1];
  const float* Wq = (const float*)d_in[2];
  const float* Wk = (const float*)d_in[3];
  const float* Wv = (const float*)d_in[4];
  const float* Wm = (const float*)d_in[5];
  const float* W1 = (const float*)d_in[6];
  const float* W2 = (const float*)d_in[7];
  const float* g1 = (const float*)d_in[8];
  const float* b1 = (const float*)d_in[9];
  const float* g2 = (const float*)d_in[10];
  const float* b2 = (const float*)d_in[11];
  float* out = (float*)d_out;
  char* ws = (char*)d_ws;

  constexpr int N = 8, L = 1024, S = 4096, D = 512;
  // workspace layout (bytes); peak = 231,899,136 (~221 MB)
  u16*   h   = (u16*)(ws + 0);          // [N*L,1024] bf16: x | ln1(message)
  u16*   sb  = (u16*)(ws + 16777216);   // [N*S,512] bf16 source
  u16*   WqT = (u16*)(ws + 50331648);
  u16*   WkT = (u16*)(ws + 50855936);
  u16*   WvT = (u16*)(ws + 51380224);
  u16*   WmT = (u16*)(ws + 51904512);
  u16*   W1T = (u16*)(ws + 52428800);   // [1024,1024]
  u16*   W2T = (u16*)(ws + 54525952);   // [512,1024]
  u16*   q   = (u16*)(ws + 55574528);   // [N*L,512]
  u16*   kb  = (u16*)(ws + 63963136);   // [N*S,512] (dead after qk gemm)
  u16*   vT  = (u16*)(ws + 97517568);   // [N][512,S] bf16 (v written transposed)
  float* lsum= (float*)(ws + 131072000);// [N*L] fp32 col sums of P
  float* q2  = (float*)(ws + 164626432);
  float* k2  = (float*)(ws + 164659200);
  u16*   qk  = (u16*)(ws + 164790272);  // [N*L,S] bf16 P = exp(dist), unnormalized
  u16*   msg = (u16*)(ws + 55574528);   // over q (dead after qk)
  float* mpart = (float*)(ws + 63963136); // [2][N*L,512] f32 over kb (dead), 32 MB
  float* mm  = (float*)(ws + 63963136); // over mpart (dead after reduce)
  u16*   hh  = (u16*)(ws + 80740352);   // 16 MB
  float* m2  = (float*)(ws + 97517568); // over vT (dead after attn.v)

  // phase 0: fused casts+zeroing, fused weight transposes
  fused_prep<<<dim3(20528), 256, 0, stream>>>(x, sc, h, sb, q2, k2, lsum);
  transpose_w6<<<dim3(32, 32, 6), dim3(32, 8), 0, stream>>>(
      Wq, Wk, Wv, Wm, W1, W2, WqT, WkT, WvT, WmT, W1T, W2T);

  // phase 1: q/k/v projections in one launch
  proj_fused<<<dim3(2304), 256, 0, stream>>>(WqT, WkT, WvT, h, sb, q, kb, vT,
                                             q2, k2);

  // phase 2: attention. EXP gemm: A=kb (rows s), Bt=q (cols l); T-store
  // lands P[l,s]; col sums -> lsum[l]. attn.v: A=vT, Bt=P, split-K=2,
  // T-store f32 -> mpart[l,c]; reduce divides by lsum.
  gemm_nt<EPI_EXP_T><<<dim3(8, 32, 8), 256, 0, stream>>>(
      kb, (size_t)S * 512, 512, q, (size_t)L * 512, 512, qk, (size_t)L * S, S,
      512, 0, q2, k2, lsum);
  gemm_nt<EPI_F32_T><<<dim3(8, 4, 16), 256, 0, stream>>>(
      vT, (size_t)D * S, S, qk, (size_t)L * S, S, mpart, (size_t)L * 512, 512,
      2048, (size_t)(N * L) * 512, nullptr, nullptr, nullptr);
  reduce2_div_bf16<<<dim3(4096), 256, 0, stream>>>(mpart, lsum, msg);

  // phase 3: message proj + LN1 into h
  gemm_nt<EPI_F32_T><<<dim3(8, 4, 8), 256, 0, stream>>>(
      WmT, 0, 512, msg, (size_t)L * 512, 512, mm, (size_t)L * 512, 512, 512, 0,
      nullptr, nullptr, nullptr);
  ln_to_h<<<dim3(N * L), 128, 0, stream>>>(mm, g1, b1, h);

  // phase 4: FFN
  gemm_nt<EPI_RELU_BF16_T><<<dim3(8, 8, 8), 256, 0, stream>>>(
      W1T, 0, 1024, h, (size_t)L * 1024, 1024, hh, (size_t)L * 1024, 1024, 1024,
      0, nullptr, nullptr, nullptr);
  gemm_nt<EPI_F32_T><<<dim3(8, 4, 8), 256, 0, stream>>>(
      W2T, 0, 1024, hh, (size_t)L * 1024, 1024, m2, (size_t)L * 512, 512, 1024,
      0, nullptr, nullptr, nullptr);

  // phase 5: LN2 + residual
  ln_residual<<<dim3(N * L), 128, 0, stream>>>(m2, x, g2, b2, out);
}